// Round 18
// baseline (229.873 us; speedup 1.0000x reference)
//
#include <hip/hip_runtime.h>
#include <hip/hip_bf16.h>

// Problem dims (fixed by the reference)
#define N_DIM 32
#define C_DIM 64
#define T_DIM 512
#define V_DIM 25
#define H_DIM 3
#define TT 8                              // t-values per t-group
#define NBLK1 2048                        // statsconv blocks
#define NBLKF 1024                        // fused blocks (2 t-groups each)
#define NTV (N_DIM * T_DIM * V_DIM)       // 409600 elements per channel
#define NTOT (N_DIM * C_DIM * T_DIM * V_DIM)
#define XPITCH 76                         // shorts per tu-row (152 B)
#define XROWS 208                         // 200 data rows + 8 zero-pad
#define SITER 13                          // staging iters (3200 / 256, ceil)
#define BN_EPS 1e-5f

typedef float f32x4 __attribute__((ext_vector_type(4)));
typedef float f32x2 __attribute__((ext_vector_type(2)));
typedef short bf16x8 __attribute__((ext_vector_type(8)));
typedef short s16x4 __attribute__((ext_vector_type(4)));

__device__ __forceinline__ short f2bf(float f) {
    __hip_bfloat16 h = __float2bfloat16(f);   // RNE; pairs fuse to v_cvt_pk_bf16_f32
    return __builtin_bit_cast(short, h);
}
__device__ __forceinline__ float bf2f(short s) {
    return __uint_as_float(((unsigned)(unsigned short)s) << 16);
}

__device__ __forceinline__ bf16x8 ld_bf8(const short* p) {   // two b64 LDS reads
    s16x4 a = *(const s16x4*)p;
    s16x4 b = *(const s16x4*)(p + 4);
    bf16x8 r;
    r[0] = a[0]; r[1] = a[1]; r[2] = a[2]; r[3] = a[3];
    r[4] = b[0]; r[5] = b[1]; r[6] = b[2]; r[7] = b[3];
    return r;
}

// ---------------------------------------------------------------------------
// Pass 0: pack W and A into per-thread MFMA fragment layout (bf16).
// wpack[b=h*2+s][tid] : o = 16*(tid>>6)+(tid&15), c = s*32+((tid>>4)&3)*8+i
// apack[b=h*2+vt][tid]: v = vt*16+(tid&15),       u = ((tid>>4)&3)*8+i  (0-pad)
// (apack works unchanged as A-operand (row=v) AND as B-operand (col=v).)
// ---------------------------------------------------------------------------
__global__ __launch_bounds__(256) void gcn_pack(
    const float* __restrict__ A, const float* __restrict__ W,
    short* __restrict__ wpack, short* __restrict__ apack)
{
    const int b   = blockIdx.x;           // 0..11
    const int tid = threadIdx.x;
    const int l15 = tid & 15, hi = (tid >> 4) & 3, w = tid >> 6;
    if (b < 6) {
        int h = b >> 1, s = b & 1;
        const float* wp = W + h * 4096 + (16 * w + l15) * 64 + s * 32 + hi * 8;
        bf16x8 f;
        #pragma unroll
        for (int i = 0; i < 8; ++i) f[i] = f2bf(wp[i]);
        *(bf16x8*)(wpack + ((size_t)b * 256 + tid) * 8) = f;
    } else {
        int bb = b - 6, h = bb >> 1, vt = bb & 1;
        int v = vt * 16 + l15;
        bf16x8 f;
        #pragma unroll
        for (int i = 0; i < 8; ++i) {
            int u = hi * 8 + i;
            f[i] = (v < 25 && u < 25) ? f2bf(A[h * 625 + v * 25 + u]) : (short)0;
        }
        *(bf16x8*)(apack + ((size_t)bb * 256 + tid) * 8) = f;
    }
}

// ---- issue-early: launch a t-group's 52 global loads into registers
__device__ __forceinline__ void stage_load(float (&fr)[SITER][4],
                                           const float* __restrict__ xg, int tid)
{
    #pragma unroll
    for (int k = 0; k < SITER; ++k) {
        int e = tid + k * 256;
        if (k < SITER - 1 || e < 3200) {
            int cg = e / 200, tu = e - cg * 200;
            const float* p = xg + cg * 51200 + tu;   // 4 c-rows per cg
            fr[k][0] = p[0];
            fr[k][1] = p[12800];
            fr[k][2] = p[25600];
            fr[k][3] = p[38400];
        }
    }
}
// ---- write-late: vmcnt drains here, then convert + coalesced ds_write
__device__ __forceinline__ void stage_write(const float (&fr)[SITER][4],
                                            short* __restrict__ dst, int tid)
{
    #pragma unroll
    for (int k = 0; k < SITER; ++k) {
        int e = tid + k * 256;
        if (k < SITER - 1 || e < 3200) {
            int cg = e / 200, tu = e - cg * 200;
            s16x4 v; v[0] = f2bf(fr[k][0]); v[1] = f2bf(fr[k][1]);
                     v[2] = f2bf(fr[k][2]); v[3] = f2bf(fr[k][3]);
            *(s16x4*)&dst[tu * XPITCH + 4 * cg] = v;
        }
    }
}

// ---------------------------------------------------------------------------
// Kernel A: conv -> per-channel {sum, sumsq} partials ONLY (no conv stores).
// ---------------------------------------------------------------------------
__global__ __launch_bounds__(256, 4) void gcn_statsconv(
    const float* __restrict__ x, const short* __restrict__ wpack,
    const short* __restrict__ apack, float* __restrict__ partial)
{
    __shared__ __align__(16) short x_sT[XROWS * XPITCH];   // 31,616 B

    const int bid  = blockIdx.x;           // 0..2047
    const int n    = bid >> 6;
    const int tgrp = bid & 63;
    const int tid  = threadIdx.x;
    const int lane = tid & 63;
    const int w    = tid >> 6;             // wave 0..3 -> o in [16w, 16w+16)
    const int l15  = lane & 15;
    const int hi   = lane >> 4;

    {
        float fr[SITER][4];
        stage_load(fr, x + (size_t)n * 819200 + tgrp * (TT * 25), tid);
        for (int e = tid; e < 304; e += 256)
            ((int*)&x_sT[200 * XPITCH])[e] = 0;
        stage_write(fr, &x_sT[0], tid);
    }

    bf16x8 wf[H_DIM][2], af[H_DIM][2];
    #pragma unroll
    for (int h = 0; h < H_DIM; ++h)
        #pragma unroll
        for (int s = 0; s < 2; ++s) {
            wf[h][s] = *(const bf16x8*)(wpack + ((h * 2 + s) * 256 + tid) * 8);
            af[h][s] = *(const bf16x8*)(apack + ((h * 2 + s) * 256 + tid) * 8);
        }
    __syncthreads();

    const int ubase = ((l15 >> 2) * 8) + (l15 & 3);
    const int o_glob = 16 * w + l15;
    float s_tot = 0.f, q_tot = 0.f;

    #pragma unroll 2
    for (int t = 0; t < TT; ++t) {
        const short* xr0 = &x_sT[(t * 25 + ubase + 0) * XPITCH + hi * 8];
        const short* xr1 = &x_sT[(t * 25 + ubase + 4) * XPITCH + hi * 8];
        const bf16x8 xf00 = ld_bf8(xr0), xf01 = ld_bf8(xr0 + 32);
        const bf16x8 xf10 = ld_bf8(xr1), xf11 = ld_bf8(xr1 + 32);

        f32x4 acc2[2] = {f32x4{0.f,0.f,0.f,0.f}, f32x4{0.f,0.f,0.f,0.f}};

        #pragma unroll
        for (int h = 0; h < H_DIM; ++h) {
            f32x4 y0 = {0.f,0.f,0.f,0.f}, y1 = {0.f,0.f,0.f,0.f};
            y0 = __builtin_amdgcn_mfma_f32_16x16x32_bf16(xf00, wf[h][0], y0, 0,0,0);
            y0 = __builtin_amdgcn_mfma_f32_16x16x32_bf16(xf01, wf[h][1], y0, 0,0,0);
            y1 = __builtin_amdgcn_mfma_f32_16x16x32_bf16(xf10, wf[h][0], y1, 0,0,0);
            y1 = __builtin_amdgcn_mfma_f32_16x16x32_bf16(xf11, wf[h][1], y1, 0,0,0);
            bf16x8 yf;
            #pragma unroll
            for (int j = 0; j < 4; ++j) yf[j] = f2bf(y0[j]);
            #pragma unroll
            for (int j = 0; j < 4; ++j) yf[4 + j] = f2bf(y1[j]);
            acc2[0] = __builtin_amdgcn_mfma_f32_16x16x32_bf16(af[h][0], yf, acc2[0], 0,0,0);
            acc2[1] = __builtin_amdgcn_mfma_f32_16x16x32_bf16(af[h][1], yf, acc2[1], 0,0,0);
        }

        float s = acc2[0][0] + acc2[0][1] + acc2[0][2] + acc2[0][3];
        float qq = fmaf(acc2[0][0], acc2[0][0], fmaf(acc2[0][1], acc2[0][1],
                   fmaf(acc2[0][2], acc2[0][2], acc2[0][3] * acc2[0][3])));
        if (hi < 2) {
            #pragma unroll
            for (int j = 0; j < 4; ++j) {
                float v1 = acc2[1][j]; s += v1; qq = fmaf(v1, v1, qq);
            }
        } else if (hi == 2) {
            float v1 = acc2[1][0]; s += v1; qq = fmaf(v1, v1, qq);
        }
        s_tot += s; q_tot += qq;
    }

    s_tot += __shfl_xor(s_tot, 16); q_tot += __shfl_xor(q_tot, 16);
    s_tot += __shfl_xor(s_tot, 32); q_tot += __shfl_xor(q_tot, 32);
    if (hi == 0) {
        partial[bid * 128 + o_glob]      = s_tot;
        partial[bid * 128 + 64 + o_glob] = q_tot;
    }
}

// ---------------------------------------------------------------------------
// Pass 2: reduce partials -> per-channel BN affine params gm, bc.
// ---------------------------------------------------------------------------
__global__ __launch_bounds__(256) void gcn_stats(
    const float* __restrict__ partial, const float* __restrict__ gamma,
    const float* __restrict__ beta, float* __restrict__ stats2)
{
    const int o = blockIdx.x;      // 64 blocks, one per channel
    const int tid = threadIdx.x;
    float s = 0.f, q = 0.f;
    for (int blk = tid; blk < NBLK1; blk += 256) {
        s += partial[blk * 128 + o];
        q += partial[blk * 128 + 64 + o];
    }
    __shared__ float rs_[256], rq_[256];
    rs_[tid] = s; rq_[tid] = q;
    __syncthreads();
    for (int off = 128; off > 0; off >>= 1) {
        if (tid < off) { rs_[tid] += rs_[tid + off]; rq_[tid] += rq_[tid + off]; }
        __syncthreads();
    }
    if (tid == 0) {
        float mean = rs_[0] / (float)NTV;
        float var  = rq_[0] / (float)NTV - mean * mean;   // biased, like jnp.var
        float gm = gamma[o] * rsqrtf(var + BN_EPS);
        stats2[o]      = gm;
        stats2[64 + o] = beta[o] - gm * mean;
    }
}

// ---------------------------------------------------------------------------
// Kernel C (spill-safe GPB=2): RECOMPUTE conv + BN + residual + ReLU.
// Each block = 2 adjacent t-groups -> per o it writes 400 contiguous floats
// = 1600 B = exactly 25 line-aligned cache lines (no cross-block sharing).
// SPILL FIX (R15/R16 lesson): fr[52] and wf/af[48] lifetimes are DISJOINT —
// fr is scoped to the staging block, and wf/af are RE-LOADED from the packs
// (12 coalesced 16B L2 loads, trivial) after every group's staging, so the
// allocator can reuse the same registers. Staging-phase peak ~70 VGPR,
// compute-phase peak ~95 — both fit the 128-cap of bounds(256,4).
// bf16 rs slices (R13-verified numerics) -> LDS 38 KB -> 4 blocks/CU.
// GEMM2 swapped (mfma(yf, af)) -> D[o][v]; epilogue: BN -> bf16 LDS slice,
// then 400 u32 (2xbf16) reads + bf16 residual from x_sT -> dense f32x2 store.
// ---------------------------------------------------------------------------
__global__ __launch_bounds__(256, 4) void gcn_fused(
    const float* __restrict__ x, const short* __restrict__ wpack,
    const short* __restrict__ apack, const float* __restrict__ stats2,
    float* __restrict__ out)
{
    __shared__ __align__(16) short x_sT[XROWS * XPITCH];   // 31,616 B
    __shared__ __align__(16) short rsb[4][800];            //  6,400 B

    const int bid  = blockIdx.x;           // 0..1023
    const int n    = bid >> 5;
    const int qp   = bid & 31;             // t-group pair: tgrp = qp*2 + g
    const int tid  = threadIdx.x;
    const int lane = tid & 63;
    const int w    = tid >> 6;
    const int l15  = lane & 15;
    const int hi   = lane >> 4;

    // BN affine params for this lane's 4 o-rows (o = 16w + hi*4 + j)
    float gm[4], bc[4];
    #pragma unroll
    for (int j = 0; j < 4; ++j) {
        int o = 16 * w + hi * 4 + j;
        gm[j] = stats2[o];
        bc[j] = stats2[64 + o];
    }

    const int ubase = ((l15 >> 2) * 8) + (l15 & 3);
    short* rw = &rsb[w][0];

    // zero pad rows once (staging never writes them)
    for (int e = tid; e < 304; e += 256)
        ((int*)&x_sT[200 * XPITCH])[e] = 0;

    #pragma unroll 1
    for (int g = 0; g < 2; ++g) {
        const int tgrp = qp * 2 + g;
        if (g) __syncthreads();            // all reads of previous tile done

        // ---- staging phase: fr lifetime fully contained here
        {
            float fr[SITER][4];
            stage_load(fr, x + (size_t)n * 819200 + tgrp * (TT * 25), tid);
            stage_write(fr, &x_sT[0], tid);
        }
        __syncthreads();                   // tile staged

        // ---- compute phase: wf/af re-loaded AFTER staging each group so
        //      their registers are dead during the next group's staging.
        bf16x8 wf[H_DIM][2], af[H_DIM][2];
        #pragma unroll
        for (int h = 0; h < H_DIM; ++h)
            #pragma unroll
            for (int s = 0; s < 2; ++s) {
                wf[h][s] = *(const bf16x8*)(wpack + ((h * 2 + s) * 256 + tid) * 8);
                af[h][s] = *(const bf16x8*)(apack + ((h * 2 + s) * 256 + tid) * 8);
            }

        const size_t ob = (size_t)n * 819200 + (size_t)(16 * w) * 12800
                        + (size_t)tgrp * 200;

        #pragma unroll
        for (int tc = 0; tc < 4; ++tc) {
            f32x4 accA[2], accB[2];

            #pragma unroll
            for (int tl = 0; tl < 2; ++tl) {
                const int t = tc * 2 + tl;
                const short* xr0 = &x_sT[(t * 25 + ubase + 0) * XPITCH + hi * 8];
                const short* xr1 = &x_sT[(t * 25 + ubase + 4) * XPITCH + hi * 8];
                const bf16x8 xf00 = ld_bf8(xr0), xf01 = ld_bf8(xr0 + 32);
                const bf16x8 xf10 = ld_bf8(xr1), xf11 = ld_bf8(xr1 + 32);

                f32x4 aA = {0.f,0.f,0.f,0.f}, aB = {0.f,0.f,0.f,0.f};
                #pragma unroll
                for (int h = 0; h < H_DIM; ++h) {
                    f32x4 y0 = {0.f,0.f,0.f,0.f}, y1 = {0.f,0.f,0.f,0.f};
                    y0 = __builtin_amdgcn_mfma_f32_16x16x32_bf16(xf00, wf[h][0], y0, 0,0,0);
                    y0 = __builtin_amdgcn_mfma_f32_16x16x32_bf16(xf01, wf[h][1], y0, 0,0,0);
                    y1 = __builtin_amdgcn_mfma_f32_16x16x32_bf16(xf10, wf[h][0], y1, 0,0,0);
                    y1 = __builtin_amdgcn_mfma_f32_16x16x32_bf16(xf11, wf[h][1], y1, 0,0,0);
                    bf16x8 yf;
                    #pragma unroll
                    for (int j = 0; j < 4; ++j) yf[j] = f2bf(y0[j]);
                    #pragma unroll
                    for (int j = 0; j < 4; ++j) yf[4 + j] = f2bf(y1[j]);
                    // swapped: yf as A-op (rows o=l15), af as B-op (cols v)
                    aA = __builtin_amdgcn_mfma_f32_16x16x32_bf16(yf, af[h][0], aA, 0,0,0);
                    aB = __builtin_amdgcn_mfma_f32_16x16x32_bf16(yf, af[h][1], aB, 0,0,0);
                }
                accA[tl] = aA; accB[tl] = aB;
            }

            // ---- epilogue phase 1: BN -> wave-private bf16 LDS slice
            #pragma unroll
            for (int tl = 0; tl < 2; ++tl)
                #pragma unroll
                for (int j = 0; j < 4; ++j) {
                    int row = (hi * 4 + j) * 50 + tl * 25;
                    rw[row + l15] = f2bf(fmaf(gm[j], accA[tl][j], bc[j]));
                    if (l15 < 9)
                        rw[row + 16 + l15] = f2bf(fmaf(gm[j], accB[tl][j], bc[j]));
                }

            // ---- epilogue phase 2: stream 400 float2 (dense, coalesced)
            #pragma unroll
            for (int k = 0; k < 7; ++k) {
                int fi = lane + k * 64;
                if (fi < 400) {
                    int o_loc = fi / 25;
                    int pp    = fi - o_loc * 25;      // float2 index in 50-run
                    unsigned pv = *(const unsigned*)&rw[fi * 2];
                    float r0 = __uint_as_float(pv << 16);
                    float r1 = __uint_as_float(pv & 0xFFFF0000u);
                    int tu = tc * 50 + pp * 2;        // position in 200-run
                    float xr0 = bf2f(x_sT[tu * XPITCH + 16 * w + o_loc]);
                    float xr1 = bf2f(x_sT[(tu + 1) * XPITCH + 16 * w + o_loc]);
                    f32x2 ov;
                    ov[0] = fmaxf(r0 + xr0, 0.f);
                    ov[1] = fmaxf(r1 + xr1, 0.f);
                    *(f32x2*)(out + ob + (size_t)o_loc * 12800 + tu) = ov;
                }
            }
        }
    }
}

// ---------------------------------------------------------------------------
// Fallback path (tiny ws): direct fp32 conv store + elementwise BN.
// ---------------------------------------------------------------------------
__global__ __launch_bounds__(256, 4) void gcn_pass1_f(
    const float* __restrict__ x, const float* __restrict__ A,
    const float* __restrict__ W, float* __restrict__ out_pre,
    float* __restrict__ partial)
{
    __shared__ __align__(16) short x_sT[XROWS * XPITCH];

    const int bid  = blockIdx.x;
    const int n    = bid >> 6;
    const int tgrp = bid & 63;
    const int tid  = threadIdx.x;
    const int lane = tid & 63;
    const int w    = tid >> 6;
    const int l15  = lane & 15;
    const int hi   = lane >> 4;

    {
        float fr[SITER][4];
        stage_load(fr, x + (size_t)n * 819200 + tgrp * (TT * 25), tid);
        for (int e = tid; e < 304; e += 256)
            ((int*)&x_sT[200 * XPITCH])[e] = 0;
        stage_write(fr, &x_sT[0], tid);
    }

    bf16x8 wf[H_DIM][2], af[H_DIM][2];
    #pragma unroll
    for (int h = 0; h < H_DIM; ++h)
        #pragma unroll
        for (int s = 0; s < 2; ++s) {
            const f32x4* wp = (const f32x4*)(W + h * 4096 + (16 * w + l15) * 64
                                             + s * 32 + hi * 8);
            f32x4 lo = wp[0], hv = wp[1];
            bf16x8 f;
            #pragma unroll
            for (int i = 0; i < 4; ++i) { f[i] = f2bf(lo[i]); f[4+i] = f2bf(hv[i]); }
            wf[h][s] = f;
            int v = s * 16 + l15;
            bf16x8 g;
            #pragma unroll
            for (int i = 0; i < 8; ++i) {
                int u = hi * 8 + i;
                g[i] = (v < 25 && u < 25) ? f2bf(A[h * 625 + v * 25 + u]) : (short)0;
            }
            af[h][s] = g;
        }
    __syncthreads();

    const int ubase = ((l15 >> 2) * 8) + (l15 & 3);
    const int o_glob = 16 * w + l15;
    float s_tot = 0.f, q_tot = 0.f;

    for (int t = 0; t < TT; ++t) {
        const short* xr0 = &x_sT[(t * 25 + ubase + 0) * XPITCH + hi * 8];
        const short* xr1 = &x_sT[(t * 25 + ubase + 4) * XPITCH + hi * 8];
        const bf16x8 xf00 = ld_bf8(xr0), xf01 = ld_bf8(xr0 + 32);
        const bf16x8 xf10 = ld_bf8(xr1), xf11 = ld_bf8(xr1 + 32);

        f32x4 acc2[2] = {f32x4{0.f,0.f,0.f,0.f}, f32x4{0.f,0.f,0.f,0.f}};
        #pragma unroll
        for (int h = 0; h < H_DIM; ++h) {
            f32x4 y0 = {0.f,0.f,0.f,0.f}, y1 = {0.f,0.f,0.f,0.f};
            y0 = __builtin_amdgcn_mfma_f32_16x16x32_bf16(xf00, wf[h][0], y0, 0,0,0);
            y0 = __builtin_amdgcn_mfma_f32_16x16x32_bf16(xf01, wf[h][1], y0, 0,0,0);
            y1 = __builtin_amdgcn_mfma_f32_16x16x32_bf16(xf10, wf[h][0], y1, 0,0,0);
            y1 = __builtin_amdgcn_mfma_f32_16x16x32_bf16(xf11, wf[h][1], y1, 0,0,0);
            bf16x8 yf;
            #pragma unroll
            for (int j = 0; j < 4; ++j) yf[j] = f2bf(y0[j]);
            #pragma unroll
            for (int j = 0; j < 4; ++j) yf[4 + j] = f2bf(y1[j]);
            acc2[0] = __builtin_amdgcn_mfma_f32_16x16x32_bf16(af[h][0], yf, acc2[0], 0,0,0);
            acc2[1] = __builtin_amdgcn_mfma_f32_16x16x32_bf16(af[h][1], yf, acc2[1], 0,0,0);
        }

        float* op = out_pre + ((size_t)(n * 64 + o_glob) * 512 + tgrp * TT + t) * 25;
        #pragma unroll
        for (int j = 0; j < 4; ++j) op[hi * 4 + j] = acc2[0][j];
        if (hi < 2) {
            #pragma unroll
            for (int j = 0; j < 4; ++j) op[16 + hi * 4 + j] = acc2[1][j];
        } else if (hi == 2) {
            op[24] = acc2[1][0];
        }

        float s = acc2[0][0] + acc2[0][1] + acc2[0][2] + acc2[0][3];
        float qq = fmaf(acc2[0][0], acc2[0][0], fmaf(acc2[0][1], acc2[0][1],
                   fmaf(acc2[0][2], acc2[0][2], acc2[0][3] * acc2[0][3])));
        if (hi < 2) {
            #pragma unroll
            for (int j = 0; j < 4; ++j) {
                float v1 = acc2[1][j]; s += v1; qq = fmaf(v1, v1, qq);
            }
        } else if (hi == 2) {
            float v1 = acc2[1][0]; s += v1; qq = fmaf(v1, v1, qq);
        }
        s_tot += s; q_tot += qq;
    }

    s_tot += __shfl_xor(s_tot, 16); q_tot += __shfl_xor(q_tot, 16);
    s_tot += __shfl_xor(s_tot, 32); q_tot += __shfl_xor(q_tot, 32);
    if (hi == 0) {
        partial[bid * 128 + o_glob]      = s_tot;
        partial[bid * 128 + 64 + o_glob] = q_tot;
    }
}

__global__ __launch_bounds__(256) void gcn_finalize_f(
    const float* __restrict__ x, const float* __restrict__ stats2,
    float* __restrict__ out)
{
    const int total4 = NTOT / 4;
    for (int i = blockIdx.x * blockDim.x + threadIdx.x; i < total4;
         i += gridDim.x * blockDim.x) {
        int chan = ((i * 4) / (T_DIM * V_DIM)) & 63;
        float4 p  = ((const float4*)out)[i];
        float4 xv = ((const float4*)x)[i];
        float g = stats2[chan], bc = stats2[64 + chan];
        p.x = fmaxf(fmaf(g, p.x, bc) + xv.x, 0.f);
        p.y = fmaxf(fmaf(g, p.y, bc) + xv.y, 0.f);
        p.z = fmaxf(fmaf(g, p.z, bc) + xv.z, 0.f);
        p.w = fmaxf(fmaf(g, p.w, bc) + xv.w, 0.f);
        ((float4*)out)[i] = p;
    }
}

extern "C" void kernel_launch(void* const* d_in, const int* in_sizes, int n_in,
                              void* d_out, int out_size, void* d_ws, size_t ws_size,
                              hipStream_t stream) {
    const float* x     = (const float*)d_in[0];
    const float* A     = (const float*)d_in[1];
    const float* W     = (const float*)d_in[2];
    // d_in[3] = b : unused — per-channel bias cancels exactly through BatchNorm
    const float* gamma = (const float*)d_in[4];
    const float* beta  = (const float*)d_in[5];
    float* out = (float*)d_out;

    const size_t part_bytes  = (size_t)NBLK1 * 128 * 4;   // 1,048,576
    const size_t stats_bytes = 512;
    const size_t pack_bytes  = 2 * 6 * 256 * 8 * 2;       // 49,152

    float* partial = (float*)d_ws;
    float* stats2  = partial + NBLK1 * 128;
    short* wpack   = (short*)((char*)d_ws + part_bytes + stats_bytes);
    short* apack   = wpack + 6 * 256 * 8;

    if (ws_size >= part_bytes + stats_bytes + pack_bytes) {
        gcn_pack<<<12, 256, 0, stream>>>(A, W, wpack, apack);
        gcn_statsconv<<<NBLK1, 256, 0, stream>>>(x, wpack, apack, partial);
        gcn_stats<<<64, 256, 0, stream>>>(partial, gamma, beta, stats2);
        gcn_fused<<<NBLKF, 256, 0, stream>>>(x, wpack, apack, stats2, out);
    } else {
        // minimal-ws fallback: conv->out (fp32), stats, in-place BN+res+relu
        gcn_pass1_f<<<NBLK1, 256, 0, stream>>>(x, A, W, out, partial);
        gcn_stats<<<64, 256, 0, stream>>>(partial, gamma, beta, stats2);
        gcn_finalize_f<<<2048, 256, 0, stream>>>(x, stats2, out);
    }
}

// Round 19
// 83.548 us; speedup vs baseline: 2.7514x; 2.7514x over previous
//
#include <hip/hip_runtime.h>
#include <hip/hip_bf16.h>

// Problem dims (fixed by the reference)
#define N_DIM 32
#define C_DIM 64
#define T_DIM 512
#define V_DIM 25
#define H_DIM 3
#define TT 8                              // t-values per block (one t-group)
#define NBLK1 2048                        // conv blocks (A and C)
#define NTV (N_DIM * T_DIM * V_DIM)       // 409600 elements per channel
#define NTOT (N_DIM * C_DIM * T_DIM * V_DIM)
#define XPITCH 76                         // shorts per tu-row (152 B)
#define XROWS 208                         // 200 data rows + 8 zero-pad
#define SITER 13                          // staging iters (3200 / 256, ceil)
#define BN_EPS 1e-5f

typedef float f32x4 __attribute__((ext_vector_type(4)));
typedef float f32x2 __attribute__((ext_vector_type(2)));
typedef short bf16x8 __attribute__((ext_vector_type(8)));
typedef short s16x4 __attribute__((ext_vector_type(4)));

__device__ __forceinline__ short f2bf(float f) {
    __hip_bfloat16 h = __float2bfloat16(f);   // RNE; pairs fuse to v_cvt_pk_bf16_f32
    return __builtin_bit_cast(short, h);
}
__device__ __forceinline__ float bf2f(short s) {
    return __uint_as_float(((unsigned)(unsigned short)s) << 16);
}

__device__ __forceinline__ bf16x8 ld_bf8(const short* p) {   // two b64 LDS reads
    s16x4 a = *(const s16x4*)p;
    s16x4 b = *(const s16x4*)(p + 4);
    bf16x8 r;
    r[0] = a[0]; r[1] = a[1]; r[2] = a[2]; r[3] = a[3];
    r[4] = b[0]; r[5] = b[1]; r[6] = b[2]; r[7] = b[3];
    return r;
}

// ---------------------------------------------------------------------------
// Pass 0: pack W and A into per-thread MFMA fragment layout (bf16).
// wpack[b=h*2+s][tid] : o = 16*(tid>>6)+(tid&15), c = s*32+((tid>>4)&3)*8+i
// apack[b=h*2+vt][tid]: v = vt*16+(tid&15),       u = ((tid>>4)&3)*8+i  (0-pad)
// (apack works unchanged as A-operand (row=v) AND as B-operand (col=v).)
// ---------------------------------------------------------------------------
__global__ __launch_bounds__(256) void gcn_pack(
    const float* __restrict__ A, const float* __restrict__ W,
    short* __restrict__ wpack, short* __restrict__ apack)
{
    const int b   = blockIdx.x;           // 0..11
    const int tid = threadIdx.x;
    const int l15 = tid & 15, hi = (tid >> 4) & 3, w = tid >> 6;
    if (b < 6) {
        int h = b >> 1, s = b & 1;
        const float* wp = W + h * 4096 + (16 * w + l15) * 64 + s * 32 + hi * 8;
        bf16x8 f;
        #pragma unroll
        for (int i = 0; i < 8; ++i) f[i] = f2bf(wp[i]);
        *(bf16x8*)(wpack + ((size_t)b * 256 + tid) * 8) = f;
    } else {
        int bb = b - 6, h = bb >> 1, vt = bb & 1;
        int v = vt * 16 + l15;
        bf16x8 f;
        #pragma unroll
        for (int i = 0; i < 8; ++i) {
            int u = hi * 8 + i;
            f[i] = (v < 25 && u < 25) ? f2bf(A[h * 625 + v * 25 + u]) : (short)0;
        }
        *(bf16x8*)(apack + ((size_t)bb * 256 + tid) * 8) = f;
    }
}

// ---- issue-early: launch the t-group's 52 global loads into registers
__device__ __forceinline__ void stage_load(float (&fr)[SITER][4],
                                           const float* __restrict__ xg, int tid)
{
    #pragma unroll
    for (int k = 0; k < SITER; ++k) {
        int e = tid + k * 256;
        if (k < SITER - 1 || e < 3200) {
            int cg = e / 200, tu = e - cg * 200;
            const float* p = xg + cg * 51200 + tu;   // 4 c-rows per cg
            fr[k][0] = p[0];
            fr[k][1] = p[12800];
            fr[k][2] = p[25600];
            fr[k][3] = p[38400];
        }
    }
}
// ---- write-late: vmcnt drains here, then convert + coalesced ds_write
__device__ __forceinline__ void stage_write(const float (&fr)[SITER][4],
                                            short* __restrict__ dst, int tid)
{
    #pragma unroll
    for (int k = 0; k < SITER; ++k) {
        int e = tid + k * 256;
        if (k < SITER - 1 || e < 3200) {
            int cg = e / 200, tu = e - cg * 200;
            s16x4 v; v[0] = f2bf(fr[k][0]); v[1] = f2bf(fr[k][1]);
                     v[2] = f2bf(fr[k][2]); v[3] = f2bf(fr[k][3]);
            *(s16x4*)&dst[tu * XPITCH + 4 * cg] = v;
        }
    }
}

// ---------------------------------------------------------------------------
// Kernel A: conv -> per-channel {sum, sumsq} partials ONLY (no conv stores).
// ---------------------------------------------------------------------------
__global__ __launch_bounds__(256, 4) void gcn_statsconv(
    const float* __restrict__ x, const short* __restrict__ wpack,
    const short* __restrict__ apack, float* __restrict__ partial)
{
    __shared__ __align__(16) short x_sT[XROWS * XPITCH];   // 31,616 B

    const int bid  = blockIdx.x;           // 0..2047
    const int n    = bid >> 6;
    const int tgrp = bid & 63;
    const int tid  = threadIdx.x;
    const int lane = tid & 63;
    const int w    = tid >> 6;             // wave 0..3 -> o in [16w, 16w+16)
    const int l15  = lane & 15;
    const int hi   = lane >> 4;

    {
        float fr[SITER][4];
        stage_load(fr, x + (size_t)n * 819200 + tgrp * (TT * 25), tid);
        for (int e = tid; e < 304; e += 256)
            ((int*)&x_sT[200 * XPITCH])[e] = 0;
        stage_write(fr, &x_sT[0], tid);
    }

    bf16x8 wf[H_DIM][2], af[H_DIM][2];
    #pragma unroll
    for (int h = 0; h < H_DIM; ++h)
        #pragma unroll
        for (int s = 0; s < 2; ++s) {
            wf[h][s] = *(const bf16x8*)(wpack + ((h * 2 + s) * 256 + tid) * 8);
            af[h][s] = *(const bf16x8*)(apack + ((h * 2 + s) * 256 + tid) * 8);
        }
    __syncthreads();

    const int ubase = ((l15 >> 2) * 8) + (l15 & 3);
    const int o_glob = 16 * w + l15;
    float s_tot = 0.f, q_tot = 0.f;

    #pragma unroll 2
    for (int t = 0; t < TT; ++t) {
        const short* xr0 = &x_sT[(t * 25 + ubase + 0) * XPITCH + hi * 8];
        const short* xr1 = &x_sT[(t * 25 + ubase + 4) * XPITCH + hi * 8];
        const bf16x8 xf00 = ld_bf8(xr0), xf01 = ld_bf8(xr0 + 32);
        const bf16x8 xf10 = ld_bf8(xr1), xf11 = ld_bf8(xr1 + 32);

        f32x4 acc2[2] = {f32x4{0.f,0.f,0.f,0.f}, f32x4{0.f,0.f,0.f,0.f}};

        #pragma unroll
        for (int h = 0; h < H_DIM; ++h) {
            f32x4 y0 = {0.f,0.f,0.f,0.f}, y1 = {0.f,0.f,0.f,0.f};
            y0 = __builtin_amdgcn_mfma_f32_16x16x32_bf16(xf00, wf[h][0], y0, 0,0,0);
            y0 = __builtin_amdgcn_mfma_f32_16x16x32_bf16(xf01, wf[h][1], y0, 0,0,0);
            y1 = __builtin_amdgcn_mfma_f32_16x16x32_bf16(xf10, wf[h][0], y1, 0,0,0);
            y1 = __builtin_amdgcn_mfma_f32_16x16x32_bf16(xf11, wf[h][1], y1, 0,0,0);
            bf16x8 yf;
            #pragma unroll
            for (int j = 0; j < 4; ++j) yf[j] = f2bf(y0[j]);
            #pragma unroll
            for (int j = 0; j < 4; ++j) yf[4 + j] = f2bf(y1[j]);
            acc2[0] = __builtin_amdgcn_mfma_f32_16x16x32_bf16(af[h][0], yf, acc2[0], 0,0,0);
            acc2[1] = __builtin_amdgcn_mfma_f32_16x16x32_bf16(af[h][1], yf, acc2[1], 0,0,0);
        }

        float s = acc2[0][0] + acc2[0][1] + acc2[0][2] + acc2[0][3];
        float qq = fmaf(acc2[0][0], acc2[0][0], fmaf(acc2[0][1], acc2[0][1],
                   fmaf(acc2[0][2], acc2[0][2], acc2[0][3] * acc2[0][3])));
        if (hi < 2) {
            #pragma unroll
            for (int j = 0; j < 4; ++j) {
                float v1 = acc2[1][j]; s += v1; qq = fmaf(v1, v1, qq);
            }
        } else if (hi == 2) {
            float v1 = acc2[1][0]; s += v1; qq = fmaf(v1, v1, qq);
        }
        s_tot += s; q_tot += qq;
    }

    s_tot += __shfl_xor(s_tot, 16); q_tot += __shfl_xor(q_tot, 16);
    s_tot += __shfl_xor(s_tot, 32); q_tot += __shfl_xor(q_tot, 32);
    if (hi == 0) {
        partial[bid * 128 + o_glob]      = s_tot;
        partial[bid * 128 + 64 + o_glob] = q_tot;
    }
}

// ---------------------------------------------------------------------------
// Pass 2: reduce partials -> per-channel BN affine params gm, bc.
// ---------------------------------------------------------------------------
__global__ __launch_bounds__(256) void gcn_stats(
    const float* __restrict__ partial, const float* __restrict__ gamma,
    const float* __restrict__ beta, float* __restrict__ stats2)
{
    const int o = blockIdx.x;      // 64 blocks, one per channel
    const int tid = threadIdx.x;
    float s = 0.f, q = 0.f;
    for (int blk = tid; blk < NBLK1; blk += 256) {
        s += partial[blk * 128 + o];
        q += partial[blk * 128 + 64 + o];
    }
    __shared__ float rs_[256], rq_[256];
    rs_[tid] = s; rq_[tid] = q;
    __syncthreads();
    for (int off = 128; off > 0; off >>= 1) {
        if (tid < off) { rs_[tid] += rs_[tid + off]; rq_[tid] += rq_[tid + off]; }
        __syncthreads();
    }
    if (tid == 0) {
        float mean = rs_[0] / (float)NTV;
        float var  = rq_[0] / (float)NTV - mean * mean;   // biased, like jnp.var
        float gm = gamma[o] * rsqrtf(var + BN_EPS);
        stats2[o]      = gm;
        stats2[64 + o] = beta[o] - gm * mean;
    }
}

// ---------------------------------------------------------------------------
// Kernel C (R12/R17 exact, verified 83.7us): RECOMPUTE conv + BN + residual
// + ReLU + coalesced store.
// GEMM2 swapped (mfma(yf, af)) -> D[o][v], lane holds v=l15 for o=16w+hi*4+j.
// t processed in 4 chunks of 2. Per chunk (wave-private, no barriers):
//   1) BN-apply acc in regs, scalar-write into this wave's fp32 LDS slice
//   2) stream 400 float2 per wave: dense LDS read + bf16 residual from x_sT
//      + relu -> contiguous float2 global stores (dense per-chunk coverage;
//      L2 merges chunk-boundary half-lines at 3 blocks/CU).
// DO NOT restructure: fr[52] scope must END before wf/af load (R15/16/18:
// any overlap — including LICM-hoisted reloads — spills to scratch).
// ---------------------------------------------------------------------------
__global__ __launch_bounds__(256, 3) void gcn_fused(
    const float* __restrict__ x, const short* __restrict__ wpack,
    const short* __restrict__ apack, const float* __restrict__ stats2,
    float* __restrict__ out)
{
    __shared__ __align__(16) short x_sT[XROWS * XPITCH];   // 31,616 B
    __shared__ __align__(16) float rs[4][800];             // 12,800 B

    const int bid  = blockIdx.x;           // 0..2047
    const int n    = bid >> 6;
    const int tgrp = bid & 63;
    const int tid  = threadIdx.x;
    const int lane = tid & 63;
    const int w    = tid >> 6;
    const int l15  = lane & 15;
    const int hi   = lane >> 4;

    {
        float fr[SITER][4];
        stage_load(fr, x + (size_t)n * 819200 + tgrp * (TT * 25), tid);
        for (int e = tid; e < 304; e += 256)
            ((int*)&x_sT[200 * XPITCH])[e] = 0;
        stage_write(fr, &x_sT[0], tid);
    }

    bf16x8 wf[H_DIM][2], af[H_DIM][2];
    #pragma unroll
    for (int h = 0; h < H_DIM; ++h)
        #pragma unroll
        for (int s = 0; s < 2; ++s) {
            wf[h][s] = *(const bf16x8*)(wpack + ((h * 2 + s) * 256 + tid) * 8);
            af[h][s] = *(const bf16x8*)(apack + ((h * 2 + s) * 256 + tid) * 8);
        }

    // BN affine params for this lane's 4 o-rows (o = 16w + hi*4 + j)
    float gm[4], bc[4];
    #pragma unroll
    for (int j = 0; j < 4; ++j) {
        int o = 16 * w + hi * 4 + j;
        gm[j] = stats2[o];
        bc[j] = stats2[64 + o];
    }
    __syncthreads();

    const int ubase = ((l15 >> 2) * 8) + (l15 & 3);
    float* rw = &rs[w][0];
    // out base for this (n, tgrp) and this wave's o range
    const size_t ob = (size_t)n * 819200 + (size_t)(16 * w) * 12800
                    + (size_t)tgrp * 200;

    #pragma unroll
    for (int tc = 0; tc < 4; ++tc) {
        f32x4 accA[2], accB[2];

        #pragma unroll
        for (int tl = 0; tl < 2; ++tl) {
            const int t = tc * 2 + tl;
            const short* xr0 = &x_sT[(t * 25 + ubase + 0) * XPITCH + hi * 8];
            const short* xr1 = &x_sT[(t * 25 + ubase + 4) * XPITCH + hi * 8];
            const bf16x8 xf00 = ld_bf8(xr0), xf01 = ld_bf8(xr0 + 32);
            const bf16x8 xf10 = ld_bf8(xr1), xf11 = ld_bf8(xr1 + 32);

            f32x4 aA = {0.f,0.f,0.f,0.f}, aB = {0.f,0.f,0.f,0.f};
            #pragma unroll
            for (int h = 0; h < H_DIM; ++h) {
                f32x4 y0 = {0.f,0.f,0.f,0.f}, y1 = {0.f,0.f,0.f,0.f};
                y0 = __builtin_amdgcn_mfma_f32_16x16x32_bf16(xf00, wf[h][0], y0, 0,0,0);
                y0 = __builtin_amdgcn_mfma_f32_16x16x32_bf16(xf01, wf[h][1], y0, 0,0,0);
                y1 = __builtin_amdgcn_mfma_f32_16x16x32_bf16(xf10, wf[h][0], y1, 0,0,0);
                y1 = __builtin_amdgcn_mfma_f32_16x16x32_bf16(xf11, wf[h][1], y1, 0,0,0);
                bf16x8 yf;
                #pragma unroll
                for (int j = 0; j < 4; ++j) yf[j] = f2bf(y0[j]);
                #pragma unroll
                for (int j = 0; j < 4; ++j) yf[4 + j] = f2bf(y1[j]);
                // swapped: yf as A-op (rows o=l15), af as B-op (cols v)
                aA = __builtin_amdgcn_mfma_f32_16x16x32_bf16(yf, af[h][0], aA, 0,0,0);
                aB = __builtin_amdgcn_mfma_f32_16x16x32_bf16(yf, af[h][1], aB, 0,0,0);
            }
            accA[tl] = aA; accB[tl] = aB;
        }

        // ---- epilogue phase 1: BN -> wave-private LDS slice (scalar writes)
        #pragma unroll
        for (int tl = 0; tl < 2; ++tl)
            #pragma unroll
            for (int j = 0; j < 4; ++j) {
                int row = (hi * 4 + j) * 50 + tl * 25;
                rw[row + l15] = fmaf(gm[j], accA[tl][j], bc[j]);
                if (l15 < 9)
                    rw[row + 16 + l15] = fmaf(gm[j], accB[tl][j], bc[j]);
            }

        // ---- epilogue phase 2: stream 400 float2 (dense, coalesced)
        #pragma unroll
        for (int k = 0; k < 7; ++k) {
            int fi = lane + k * 64;
            if (fi < 400) {
                int o_loc = fi / 25;
                int pp    = fi - o_loc * 25;          // float2 index in 50-run
                f32x2 rv = *(const f32x2*)&rw[fi * 2];
                int tu = tc * 50 + pp * 2;            // position in 200-run
                float xr0 = bf2f(x_sT[tu * XPITCH + 16 * w + o_loc]);
                float xr1 = bf2f(x_sT[(tu + 1) * XPITCH + 16 * w + o_loc]);
                f32x2 ov;
                ov[0] = fmaxf(rv[0] + xr0, 0.f);
                ov[1] = fmaxf(rv[1] + xr1, 0.f);
                *(f32x2*)(out + ob + (size_t)o_loc * 12800 + tu) = ov;
            }
        }
    }
}

// ---------------------------------------------------------------------------
// Fallback path (tiny ws): direct fp32 conv store + elementwise BN.
// ---------------------------------------------------------------------------
__global__ __launch_bounds__(256, 4) void gcn_pass1_f(
    const float* __restrict__ x, const float* __restrict__ A,
    const float* __restrict__ W, float* __restrict__ out_pre,
    float* __restrict__ partial)
{
    __shared__ __align__(16) short x_sT[XROWS * XPITCH];

    const int bid  = blockIdx.x;
    const int n    = bid >> 6;
    const int tgrp = bid & 63;
    const int tid  = threadIdx.x;
    const int lane = tid & 63;
    const int w    = tid >> 6;
    const int l15  = lane & 15;
    const int hi   = lane >> 4;

    {
        float fr[SITER][4];
        stage_load(fr, x + (size_t)n * 819200 + tgrp * (TT * 25), tid);
        for (int e = tid; e < 304; e += 256)
            ((int*)&x_sT[200 * XPITCH])[e] = 0;
        stage_write(fr, &x_sT[0], tid);
    }

    bf16x8 wf[H_DIM][2], af[H_DIM][2];
    #pragma unroll
    for (int h = 0; h < H_DIM; ++h)
        #pragma unroll
        for (int s = 0; s < 2; ++s) {
            const f32x4* wp = (const f32x4*)(W + h * 4096 + (16 * w + l15) * 64
                                             + s * 32 + hi * 8);
            f32x4 lo = wp[0], hv = wp[1];
            bf16x8 f;
            #pragma unroll
            for (int i = 0; i < 4; ++i) { f[i] = f2bf(lo[i]); f[4+i] = f2bf(hv[i]); }
            wf[h][s] = f;
            int v = s * 16 + l15;
            bf16x8 g;
            #pragma unroll
            for (int i = 0; i < 8; ++i) {
                int u = hi * 8 + i;
                g[i] = (v < 25 && u < 25) ? f2bf(A[h * 625 + v * 25 + u]) : (short)0;
            }
            af[h][s] = g;
        }
    __syncthreads();

    const int ubase = ((l15 >> 2) * 8) + (l15 & 3);
    const int o_glob = 16 * w + l15;
    float s_tot = 0.f, q_tot = 0.f;

    for (int t = 0; t < TT; ++t) {
        const short* xr0 = &x_sT[(t * 25 + ubase + 0) * XPITCH + hi * 8];
        const short* xr1 = &x_sT[(t * 25 + ubase + 4) * XPITCH + hi * 8];
        const bf16x8 xf00 = ld_bf8(xr0), xf01 = ld_bf8(xr0 + 32);
        const bf16x8 xf10 = ld_bf8(xr1), xf11 = ld_bf8(xr1 + 32);

        f32x4 acc2[2] = {f32x4{0.f,0.f,0.f,0.f}, f32x4{0.f,0.f,0.f,0.f}};
        #pragma unroll
        for (int h = 0; h < H_DIM; ++h) {
            f32x4 y0 = {0.f,0.f,0.f,0.f}, y1 = {0.f,0.f,0.f,0.f};
            y0 = __builtin_amdgcn_mfma_f32_16x16x32_bf16(xf00, wf[h][0], y0, 0,0,0);
            y0 = __builtin_amdgcn_mfma_f32_16x16x32_bf16(xf01, wf[h][1], y0, 0,0,0);
            y1 = __builtin_amdgcn_mfma_f32_16x16x32_bf16(xf10, wf[h][0], y1, 0,0,0);
            y1 = __builtin_amdgcn_mfma_f32_16x16x32_bf16(xf11, wf[h][1], y1, 0,0,0);
            bf16x8 yf;
            #pragma unroll
            for (int j = 0; j < 4; ++j) yf[j] = f2bf(y0[j]);
            #pragma unroll
            for (int j = 0; j < 4; ++j) yf[4 + j] = f2bf(y1[j]);
            acc2[0] = __builtin_amdgcn_mfma_f32_16x16x32_bf16(af[h][0], yf, acc2[0], 0,0,0);
            acc2[1] = __builtin_amdgcn_mfma_f32_16x16x32_bf16(af[h][1], yf, acc2[1], 0,0,0);
        }

        float* op = out_pre + ((size_t)(n * 64 + o_glob) * 512 + tgrp * TT + t) * 25;
        #pragma unroll
        for (int j = 0; j < 4; ++j) op[hi * 4 + j] = acc2[0][j];
        if (hi < 2) {
            #pragma unroll
            for (int j = 0; j < 4; ++j) op[16 + hi * 4 + j] = acc2[1][j];
        } else if (hi == 2) {
            op[24] = acc2[1][0];
        }

        float s = acc2[0][0] + acc2[0][1] + acc2[0][2] + acc2[0][3];
        float qq = fmaf(acc2[0][0], acc2[0][0], fmaf(acc2[0][1], acc2[0][1],
                   fmaf(acc2[0][2], acc2[0][2], acc2[0][3] * acc2[0][3])));
        if (hi < 2) {
            #pragma unroll
            for (int j = 0; j < 4; ++j) {
                float v1 = acc2[1][j]; s += v1; qq = fmaf(v1, v1, qq);
            }
        } else if (hi == 2) {
            float v1 = acc2[1][0]; s += v1; qq = fmaf(v1, v1, qq);
        }
        s_tot += s; q_tot += qq;
    }

    s_tot += __shfl_xor(s_tot, 16); q_tot += __shfl_xor(q_tot, 16);
    s_tot += __shfl_xor(s_tot, 32); q_tot += __shfl_xor(q_tot, 32);
    if (hi == 0) {
        partial[bid * 128 + o_glob]      = s_tot;
        partial[bid * 128 + 64 + o_glob] = q_tot;
    }
}

__global__ __launch_bounds__(256) void gcn_finalize_f(
    const float* __restrict__ x, const float* __restrict__ stats2,
    float* __restrict__ out)
{
    const int total4 = NTOT / 4;
    for (int i = blockIdx.x * blockDim.x + threadIdx.x; i < total4;
         i += gridDim.x * blockDim.x) {
        int chan = ((i * 4) / (T_DIM * V_DIM)) & 63;
        float4 p  = ((const float4*)out)[i];
        float4 xv = ((const float4*)x)[i];
        float g = stats2[chan], bc = stats2[64 + chan];
        p.x = fmaxf(fmaf(g, p.x, bc) + xv.x, 0.f);
        p.y = fmaxf(fmaf(g, p.y, bc) + xv.y, 0.f);
        p.z = fmaxf(fmaf(g, p.z, bc) + xv.z, 0.f);
        p.w = fmaxf(fmaf(g, p.w, bc) + xv.w, 0.f);
        ((float4*)out)[i] = p;
    }
}

extern "C" void kernel_launch(void* const* d_in, const int* in_sizes, int n_in,
                              void* d_out, int out_size, void* d_ws, size_t ws_size,
                              hipStream_t stream) {
    const float* x     = (const float*)d_in[0];
    const float* A     = (const float*)d_in[1];
    const float* W     = (const float*)d_in[2];
    // d_in[3] = b : unused — per-channel bias cancels exactly through BatchNorm
    const float* gamma = (const float*)d_in[4];
    const float* beta  = (const float*)d_in[5];
    float* out = (float*)d_out;

    const size_t part_bytes  = (size_t)NBLK1 * 128 * 4;   // 1,048,576
    const size_t stats_bytes = 512;
    const size_t pack_bytes  = 2 * 6 * 256 * 8 * 2;       // 49,152

    float* partial = (float*)d_ws;
    float* stats2  = partial + NBLK1 * 128;
    short* wpack   = (short*)((char*)d_ws + part_bytes + stats_bytes);
    short* apack   = wpack + 6 * 256 * 8;

    if (ws_size >= part_bytes + stats_bytes + pack_bytes) {
        gcn_pack<<<12, 256, 0, stream>>>(A, W, wpack, apack);
        gcn_statsconv<<<NBLK1, 256, 0, stream>>>(x, wpack, apack, partial);
        gcn_stats<<<64, 256, 0, stream>>>(partial, gamma, beta, stats2);
        gcn_fused<<<NBLK1, 256, 0, stream>>>(x, wpack, apack, stats2, out);
    } else {
        // minimal-ws fallback: conv->out (fp32), stats, in-place BN+res+relu
        gcn_pass1_f<<<NBLK1, 256, 0, stream>>>(x, A, W, out, partial);
        gcn_stats<<<64, 256, 0, stream>>>(partial, gamma, beta, stats2);
        gcn_finalize_f<<<2048, 256, 0, stream>>>(x, stats2, out);
    }
}